// Round 4
// baseline (287.953 us; speedup 1.0000x reference)
//
#include <hip/hip_runtime.h>
#include <hip/hip_bf16.h>
#include <stdint.h>

// ---------------- types / helpers ----------------
typedef __bf16 bf16x8 __attribute__((ext_vector_type(8)));
typedef unsigned short u16x8 __attribute__((ext_vector_type(8)));
typedef float f32x4 __attribute__((ext_vector_type(4)));

#define DMODEL 768
#define NSEQ   2048
#define BATCH  2
#define NHEAD  12
#define HDIM   64
#define HIDDEN 3072

__device__ __forceinline__ uint16_t f2bf(float f) {
  __hip_bfloat16 h = __float2bfloat16(f);
  return __builtin_bit_cast(uint16_t, h);
}
__device__ __forceinline__ bf16x8 ldb8(const uint16_t* p) {
  return __builtin_bit_cast(bf16x8, *reinterpret_cast<const u16x8*>(p));
}

using as1_void = __attribute__((address_space(1))) const void;
using as3_void = __attribute__((address_space(3))) void;
__device__ __forceinline__ void gload16(const uint16_t* src, uint16_t* lds) {
  __builtin_amdgcn_global_load_lds((as1_void*)src, (as3_void*)lds, 16, 0, 0);
}
#define MEMFENCE asm volatile("" ::: "memory")

// ---------------- fused fp32 -> bf16 casts ----------------
#define N_QKVW  (3 * DMODEL * DMODEL)
#define N_PROJW (DMODEL * DMODEL)
#define N_FC1W  (HIDDEN * DMODEL)
#define N_FC2W  (DMODEL * HIDDEN)
__global__ __launch_bounds__(256) void cvt4_kernel(const float* __restrict__ s0,
                                                   const float* __restrict__ s1,
                                                   const float* __restrict__ s2,
                                                   const float* __restrict__ s3,
                                                   uint16_t* __restrict__ d0,
                                                   uint16_t* __restrict__ d1,
                                                   uint16_t* __restrict__ d2,
                                                   uint16_t* __restrict__ d3) {
  int i4 = (blockIdx.x * 256 + threadIdx.x) * 4;
  const float* s;
  uint16_t* d;
  if (i4 < N_QKVW) { s = s0 + i4; d = d0 + i4; }
  else if (i4 < N_QKVW + N_PROJW) { int j = i4 - N_QKVW; s = s1 + j; d = d1 + j; }
  else if (i4 < N_QKVW + N_PROJW + N_FC1W) { int j = i4 - N_QKVW - N_PROJW; s = s2 + j; d = d2 + j; }
  else { int j = i4 - N_QKVW - N_PROJW - N_FC1W; s = s3 + j; d = d3 + j; }
  float4 v = *reinterpret_cast<const float4*>(s);
  ushort4 o;
  o.x = f2bf(v.x); o.y = f2bf(v.y); o.z = f2bf(v.z); o.w = f2bf(v.w);
  *reinterpret_cast<ushort4*>(d) = o;
}

// ---------------- qkv bias assembly ----------------
__global__ __launch_bounds__(256) void bias_kernel(const float* __restrict__ qb,
                                                   const float* __restrict__ vb,
                                                   float* __restrict__ out) {
  int j = blockIdx.x * 256 + threadIdx.x;
  if (j < 3 * DMODEL) {
    float v = 0.f;
    if (j < DMODEL) v = qb[j];
    else if (j >= 2 * DMODEL) v = vb[j - 2 * DMODEL];
    out[j] = v;
  }
}

// ---------------- layernorm: fp32 in -> bf16 out ----------------
__global__ __launch_bounds__(256) void ln_kernel(const float* __restrict__ x,
                                                 const float* __restrict__ g,
                                                 const float* __restrict__ bt,
                                                 uint16_t* __restrict__ out) {
  const int row = blockIdx.x;
  const int t = threadIdx.x;
  const float* xr = x + (size_t)row * DMODEL;
  float v0 = xr[t], v1 = xr[t + 256], v2 = xr[t + 512];
  float s = v0 + v1 + v2;
  float q = v0 * v0 + v1 * v1 + v2 * v2;
  for (int off = 32; off >= 1; off >>= 1) {
    s += __shfl_xor(s, off);
    q += __shfl_xor(q, off);
  }
  __shared__ float ss[4], sq[4];
  int w = t >> 6;
  if ((t & 63) == 0) { ss[w] = s; sq[w] = q; }
  __syncthreads();
  s = ss[0] + ss[1] + ss[2] + ss[3];
  q = sq[0] + sq[1] + sq[2] + sq[3];
  const float mean = s * (1.0f / DMODEL);
  const float var = q * (1.0f / DMODEL) - mean * mean;
  const float rstd = rsqrtf(var + 1e-5f);
  uint16_t* orow = out + (size_t)row * DMODEL;
  orow[t]       = f2bf((v0 - mean) * rstd * g[t]       + bt[t]);
  orow[t + 256] = f2bf((v1 - mean) * rstd * g[t + 256] + bt[t + 256]);
  orow[t + 512] = f2bf((v2 - mean) * rstd * g[t + 512] + bt[t + 512]);
}

// ---------------- GEMM: C = A * W^T + bias; 128x128 block, 2 waves x (128x64) --
// Frag-read ratio: 24 ds_read_b128 per 64 MFMA per k-step (vs 32 for 4x64x64).
template <int MODE>
__global__ __launch_bounds__(128, 2) void gemm128(const uint16_t* __restrict__ A,
                                                  const uint16_t* __restrict__ W,
                                                  const float* __restrict__ bias,
                                                  void* __restrict__ outp,
                                                  const float* __restrict__ resid,
                                                  const float* __restrict__ gamma,
                                                  int M, int N, int K) {
  __shared__ uint16_t As[2][128 * 32];
  __shared__ uint16_t Bs[2][128 * 32];
  const int tid = threadIdx.x;
  const int lane = tid & 63;
  const int wv = tid >> 6;      // 2 waves
  const int row0 = blockIdx.y * 128;
  const int col0 = blockIdx.x * 128;
  const int lr = lane & 15;
  const int g = lane >> 4;

  // staging: 128 threads x 16B = 2KB/issue; 8KB tile -> 4 issues per operand
  const int rs = tid >> 2;            // row (+ i*32)
  const int cs = (tid & 3) * 8;       // k-col (elems)
  const int dst = wv * 512;           // elems (+ i*1024)
  const uint16_t* Abase = A + (size_t)row0 * K;
  const uint16_t* Wbase = W + (size_t)col0 * K;

  auto stage = [&](int kt) {
    uint16_t* Ad = &As[kt & 1][0];
    uint16_t* Bd = &Bs[kt & 1][0];
    const int kk = kt * 32;
#pragma unroll
    for (int i = 0; i < 4; ++i)
      gload16(Abase + (size_t)(rs + i * 32) * K + kk + cs, Ad + i * 1024 + dst);
#pragma unroll
    for (int i = 0; i < 4; ++i)
      gload16(Wbase + (size_t)(rs + i * 32) * K + kk + cs, Bd + i * 1024 + dst);
  };

  f32x4 acc[8][4] = {};
  const int nt = K >> 5;
  stage(0);
  for (int kt = 0; kt < nt; ++kt) {
    if (kt + 1 < nt) {
      stage(kt + 1);
      asm volatile("s_waitcnt vmcnt(8)" ::: "memory");
    } else {
      asm volatile("s_waitcnt vmcnt(0)" ::: "memory");
    }
    __builtin_amdgcn_s_barrier();
    MEMFENCE;
    const uint16_t* Ab = &As[kt & 1][0];
    const uint16_t* Bb = &Bs[kt & 1][0];
    bf16x8 a[8], b[4];
#pragma unroll
    for (int m = 0; m < 8; ++m) a[m] = ldb8(Ab + (m * 16 + lr) * 32 + g * 8);
#pragma unroll
    for (int n = 0; n < 4; ++n) b[n] = ldb8(Bb + (wv * 64 + n * 16 + lr) * 32 + g * 8);
#pragma unroll
    for (int m = 0; m < 8; ++m)
#pragma unroll
      for (int n = 0; n < 4; ++n)
        acc[m][n] = __builtin_amdgcn_mfma_f32_16x16x32_bf16(a[m], b[n], acc[m][n], 0, 0, 0);
    MEMFENCE;
    __builtin_amdgcn_s_barrier();
  }

#pragma unroll
  for (int m = 0; m < 8; ++m) {
    int row = row0 + m * 16 + g * 4;
#pragma unroll
    for (int n = 0; n < 4; ++n) {
      int col = col0 + wv * 64 + n * 16 + lr;
      float bv = bias[col];
#pragma unroll
      for (int ri = 0; ri < 4; ++ri) {
        float val = acc[m][n][ri] + bv;
        size_t idx = (size_t)(row + ri) * N + col;
        if constexpr (MODE == 0) {
          if (col < DMODEL) val *= 0.125f;   // fold attention scale into Q
          ((uint16_t*)outp)[idx] = f2bf(val);
        } else if constexpr (MODE == 2) {
          float ge = 0.5f * val * (1.0f + erff(val * 0.70710678118654752f));
          ((uint16_t*)outp)[idx] = f2bf(ge);
        } else {
          ((float*)outp)[idx] = resid[idx] + gamma[col] * val;
        }
      }
    }
  }
}

// ---------------- V transpose (LDS-tiled, coalesced): qkv -> vt[bh][d][n] ------
__global__ __launch_bounds__(256) void vtrans_kernel(const uint16_t* __restrict__ qkv,
                                                     uint16_t* __restrict__ vt) {
  __shared__ uint16_t tile[64][72];
  const int t = threadIdx.x;
  const int bh = blockIdx.x;
  const int n0 = blockIdx.y * 64;
  const int b = bh / NHEAD, h = bh % NHEAD;
  const uint16_t* src = qkv + (size_t)(b * NSEQ + n0) * (3 * DMODEL) + 2 * DMODEL + h * HDIM;
#pragma unroll
  for (int it = 0; it < 2; ++it) {
    int slot = it * 256 + t;
    int r = slot >> 2, c = (slot & 3) * 16;
    u16x8 v0 = *reinterpret_cast<const u16x8*>(src + (size_t)r * (3 * DMODEL) + c);
    u16x8 v1 = *reinterpret_cast<const u16x8*>(src + (size_t)r * (3 * DMODEL) + c + 8);
    *reinterpret_cast<u16x8*>(&tile[r][c]) = v0;
    *reinterpret_cast<u16x8*>(&tile[r][c + 8]) = v1;
  }
  __syncthreads();
  uint16_t* dst = vt + (size_t)bh * HDIM * NSEQ + n0;
#pragma unroll
  for (int it = 0; it < 2; ++it) {
    int slot = it * 256 + t;
    int d = slot >> 2, c = (slot & 3) * 16;
    u16x8 a0, a1;
#pragma unroll
    for (int e = 0; e < 8; ++e) a0[e] = tile[c + e][d];
#pragma unroll
    for (int e = 0; e < 8; ++e) a1[e] = tile[c + 8 + e][d];
    *reinterpret_cast<u16x8*>(dst + (size_t)d * NSEQ + c) = a0;
    *reinterpret_cast<u16x8*>(dst + (size_t)d * NSEQ + c + 8) = a1;
  }
}

// ---------------- flash attention v2 -------------------------------------------
// 4 waves x 32 q-rows (two 16-row sub-tiles sharing K/V frag regs), KVBLK=64.
// LDS-staged K/V dbuf + counted vmcnt; lsum via ones-MFMA; setprio on MFMA.
__global__ __launch_bounds__(256, 2) void attn_kernel(const uint16_t* __restrict__ qkv,
                                                      const uint16_t* __restrict__ vt,
                                                      const int* __restrict__ mask,
                                                      uint16_t* __restrict__ o) {
  __shared__ uint16_t Kb[2][64 * 64];
  __shared__ uint16_t Vb[2][64 * 64];
  __shared__ __align__(16) uint16_t plds[4][2][16 * 72];
  __shared__ float sbias[NSEQ];
  const int tid = threadIdx.x;
  const int lane = tid & 63;
  const int w = tid >> 6;
  const int bh = blockIdx.x;
  const int b = bh / NHEAD, h = bh % NHEAD;
  const int q0 = blockIdx.y * 128 + w * 32;
  const int lr = lane & 15;
  const int g = lane >> 4;
  const int lk = g * 8;

  const int* mb = mask + b * NSEQ;
  for (int i = tid; i < NSEQ; i += 256) sbias[i] = mb[i] ? 0.f : -3e30f;

  bf16x8 qa[2][2];
#pragma unroll
  for (int s = 0; s < 2; ++s) {
    const uint16_t* qb = qkv + (size_t)(b * NSEQ + q0 + s * 16 + lr) * (3 * DMODEL) + h * HDIM + lk;
    qa[s][0] = ldb8(qb);
    qa[s][1] = ldb8(qb + 32);
  }
  const uint16_t* kglob = qkv + (size_t)b * NSEQ * (3 * DMODEL) + DMODEL + h * HDIM;
  const uint16_t* vtb = vt + (size_t)bh * HDIM * NSEQ;

  __syncthreads();   // sbias visible before staging

  const int srow = tid >> 3;
  const int sxor = ((tid & 7) ^ ((tid >> 3) & 7)) * 8;
  auto stage = [&](int t) {
    const int p = t & 1;
    const int k0 = t * 64;
#pragma unroll
    for (int i = 0; i < 2; ++i) {
      const int row = i * 32 + srow;
      gload16(kglob + (size_t)(k0 + row) * (3 * DMODEL) + sxor, &Kb[p][i * 2048 + w * 512]);
      gload16(vtb + (size_t)row * NSEQ + k0 + sxor, &Vb[p][i * 2048 + w * 512]);
    }
  };
  const int koff0 = ((g ^ (lr & 7))) * 8;
  const int koff1 = (((4 + g) ^ (lr & 7))) * 8;

  u16x8 ones_u;
#pragma unroll
  for (int e = 0; e < 8; ++e) ones_u[e] = 0x3F80;   // bf16 1.0
  const bf16x8 ones = __builtin_bit_cast(bf16x8, ones_u);

  float m_[2][4] = {{-1e30f, -1e30f, -1e30f, -1e30f}, {-1e30f, -1e30f, -1e30f, -1e30f}};
  f32x4 lsum[2] = {};
  f32x4 oacc[2][4] = {};

  stage(0);
  const int NT = NSEQ / 64;
  for (int t = 0; t < NT; ++t) {
    if (t + 1 < NT) {
      stage(t + 1);
      asm volatile("s_waitcnt vmcnt(4)" ::: "memory");
    } else {
      asm volatile("s_waitcnt vmcnt(0)" ::: "memory");
    }
    __builtin_amdgcn_s_barrier();
    MEMFENCE;
    const uint16_t* Kbp = &Kb[t & 1][0];
    const uint16_t* Vbp = &Vb[t & 1][0];
    const int k0 = t * 64;

    f32x4 st[2][4];
    __builtin_amdgcn_s_setprio(1);
#pragma unroll
    for (int j = 0; j < 4; ++j) {
      const uint16_t* kr = Kbp + (j * 16 + lr) * 64;
      bf16x8 kf0 = ldb8(kr + koff0);
      bf16x8 kf1 = ldb8(kr + koff1);
#pragma unroll
      for (int s = 0; s < 2; ++s) {
        f32x4 acc0 = {};
        acc0 = __builtin_amdgcn_mfma_f32_16x16x32_bf16(qa[s][0], kf0, acc0, 0, 0, 0);
        acc0 = __builtin_amdgcn_mfma_f32_16x16x32_bf16(qa[s][1], kf1, acc0, 0, 0, 0);
        st[s][j] = acc0;
      }
    }
    __builtin_amdgcn_s_setprio(0);

    float bj[4];
#pragma unroll
    for (int j = 0; j < 4; ++j) bj[j] = sbias[k0 + j * 16 + lr];

    float sv[2][4][4], tmax[2][4];
    float need = 0.f;
#pragma unroll
    for (int s = 0; s < 2; ++s)
#pragma unroll
      for (int r = 0; r < 4; ++r) {
        float tm = -1e30f;
#pragma unroll
        for (int j = 0; j < 4; ++j) {
          float sc = st[s][j][r] + bj[j];
          sv[s][r][j] = sc;
          tm = fmaxf(tm, sc);
        }
        tm = fmaxf(tm, __shfl_xor(tm, 1));
        tm = fmaxf(tm, __shfl_xor(tm, 2));
        tm = fmaxf(tm, __shfl_xor(tm, 4));
        tm = fmaxf(tm, __shfl_xor(tm, 8));
        tmax[s][r] = tm;
        need = fmaxf(need, tm - m_[s][r]);
      }
    if (__any(need > 8.0f)) {           // defer-max (T13)
#pragma unroll
      for (int s = 0; s < 2; ++s)
#pragma unroll
        for (int r = 0; r < 4; ++r) {
          float mn = fmaxf(m_[s][r], tmax[s][r]);
          float al = __expf(m_[s][r] - mn);
          lsum[s][r] *= al;
          m_[s][r] = mn;
#pragma unroll
          for (int dt = 0; dt < 4; ++dt) oacc[s][dt][r] *= al;
        }
    }
#pragma unroll
    for (int s = 0; s < 2; ++s)
#pragma unroll
      for (int r = 0; r < 4; ++r)
#pragma unroll
        for (int j = 0; j < 4; ++j) {
          float pv = __expf(sv[s][r][j] - m_[s][r]);
          plds[w][s][(g * 4 + r) * 72 + j * 16 + lr] = f2bf(pv);
        }
    bf16x8 pa[2][2];
#pragma unroll
    for (int s = 0; s < 2; ++s) {
      pa[s][0] = ldb8(&plds[w][s][lr * 72 + lk]);
      pa[s][1] = ldb8(&plds[w][s][lr * 72 + 32 + lk]);
    }
    __builtin_amdgcn_s_setprio(1);
#pragma unroll
    for (int dt = 0; dt < 4; ++dt) {
      const uint16_t* vr = Vbp + (dt * 16 + lr) * 64;
      bf16x8 vf0 = ldb8(vr + koff0);
      bf16x8 vf1 = ldb8(vr + koff1);
#pragma unroll
      for (int s = 0; s < 2; ++s) {
        oacc[s][dt] = __builtin_amdgcn_mfma_f32_16x16x32_bf16(pa[s][0], vf0, oacc[s][dt], 0, 0, 0);
        oacc[s][dt] = __builtin_amdgcn_mfma_f32_16x16x32_bf16(pa[s][1], vf1, oacc[s][dt], 0, 0, 0);
      }
    }
#pragma unroll
    for (int s = 0; s < 2; ++s) {       // row-sum via ones-MFMA (replaces shfl reduce)
      lsum[s] = __builtin_amdgcn_mfma_f32_16x16x32_bf16(pa[s][0], ones, lsum[s], 0, 0, 0);
      lsum[s] = __builtin_amdgcn_mfma_f32_16x16x32_bf16(pa[s][1], ones, lsum[s], 0, 0, 0);
    }
    __builtin_amdgcn_s_setprio(0);
    MEMFENCE;
    __builtin_amdgcn_s_barrier();
  }

#pragma unroll
  for (int s = 0; s < 2; ++s) {
    float inv[4];
#pragma unroll
    for (int r = 0; r < 4; ++r) inv[r] = lsum[s][r] > 0.f ? 1.f / lsum[s][r] : 0.f;
    uint16_t* ob = o + (size_t)(b * NSEQ + q0 + s * 16) * DMODEL + h * HDIM;
#pragma unroll
    for (int dt = 0; dt < 4; ++dt)
#pragma unroll
      for (int r = 0; r < 4; ++r)
        ob[(size_t)(g * 4 + r) * DMODEL + dt * 16 + lr] = f2bf(oacc[s][dt][r] * inv[r]);
  }
}

// ---------------- host ----------------
extern "C" void kernel_launch(void* const* d_in, const int* in_sizes, int n_in,
                              void* d_out, int out_size, void* d_ws, size_t ws_size,
                              hipStream_t stream) {
  const float* x      = (const float*)d_in[0];
  const int*   amask  = (const int*)d_in[1];
  const float* ln1_g  = (const float*)d_in[2];
  const float* ln1_b  = (const float*)d_in[3];
  const float* qkv_w  = (const float*)d_in[4];
  const float* q_bias = (const float*)d_in[5];
  const float* v_bias = (const float*)d_in[6];
  const float* proj_w = (const float*)d_in[7];
  const float* proj_b = (const float*)d_in[8];
  const float* ln2_g  = (const float*)d_in[9];
  const float* ln2_b  = (const float*)d_in[10];
  const float* fc1_w  = (const float*)d_in[11];
  const float* fc1_b  = (const float*)d_in[12];
  const float* fc2_w  = (const float*)d_in[13];
  const float* fc2_b  = (const float*)d_in[14];
  const float* g1     = (const float*)d_in[15];
  const float* g2     = (const float*)d_in[16];

  char* ws = (char*)d_ws;
  uint16_t* qkvw_bf  = (uint16_t*)(ws + 0);
  uint16_t* projw_bf = (uint16_t*)(ws + 3538944);
  uint16_t* fc1w_bf  = (uint16_t*)(ws + 4718592);
  uint16_t* fc2w_bf  = (uint16_t*)(ws + 9437184);
  float*    qkvbias  = (float*)(ws + 14155776);
  uint16_t* h_bf     = (uint16_t*)(ws + 14164992);
  uint16_t* qkv_bf   = (uint16_t*)(ws + 20456448);
  uint16_t* vt_bf    = (uint16_t*)(ws + 39330816);
  uint16_t* o_bf     = (uint16_t*)(ws + 45622272);
  float*    x1_f     = (float*)(ws + 51913728);
  uint16_t* fc1_bf   = qkv_bf;
  uint16_t* h2_bf    = h_bf;

  const int M = BATCH * NSEQ;

  cvt4_kernel<<<(N_QKVW + N_PROJW + N_FC1W + N_FC2W) / 1024, 256, 0, stream>>>(
      qkv_w, proj_w, fc1_w, fc2_w, qkvw_bf, projw_bf, fc1w_bf, fc2w_bf);
  bias_kernel<<<(3 * DMODEL + 255) / 256, 256, 0, stream>>>(q_bias, v_bias, qkvbias);

  ln_kernel<<<M, 256, 0, stream>>>(x, ln1_g, ln1_b, h_bf);
  gemm128<0><<<dim3((3 * DMODEL) / 128, M / 128), 128, 0, stream>>>(
      h_bf, qkvw_bf, qkvbias, qkv_bf, nullptr, nullptr, M, 3 * DMODEL, DMODEL);
  vtrans_kernel<<<dim3(BATCH * NHEAD, NSEQ / 64), 256, 0, stream>>>(qkv_bf, vt_bf);
  attn_kernel<<<dim3(BATCH * NHEAD, NSEQ / 128), 256, 0, stream>>>(qkv_bf, vt_bf, amask, o_bf);
  gemm128<1><<<dim3(DMODEL / 128, M / 128), 128, 0, stream>>>(
      o_bf, projw_bf, proj_b, x1_f, x, g1, M, DMODEL, DMODEL);
  ln_kernel<<<M, 256, 0, stream>>>(x1_f, ln2_g, ln2_b, h2_bf);
  gemm128<2><<<dim3(HIDDEN / 128, M / 128), 128, 0, stream>>>(
      h2_bf, fc1w_bf, fc1_b, fc1_bf, nullptr, nullptr, M, HIDDEN, DMODEL);
  gemm128<3><<<dim3(DMODEL / 128, M / 128), 128, 0, stream>>>(
      fc1_bf, fc2w_bf, fc2_b, (float*)d_out, x1_f, g2, M, DMODEL, HIDDEN);
}

// Round 5
// 256.051 us; speedup vs baseline: 1.1246x; 1.1246x over previous
//
#include <hip/hip_runtime.h>
#include <hip/hip_bf16.h>
#include <stdint.h>

// ---------------- types / helpers ----------------
typedef __bf16 bf16x8 __attribute__((ext_vector_type(8)));
typedef unsigned short u16x8 __attribute__((ext_vector_type(8)));
typedef float f32x4 __attribute__((ext_vector_type(4)));

#define DMODEL 768
#define NSEQ   2048
#define BATCH  2
#define NHEAD  12
#define HDIM   64
#define HIDDEN 3072

__device__ __forceinline__ uint16_t f2bf(float f) {
  __hip_bfloat16 h = __float2bfloat16(f);
  return __builtin_bit_cast(uint16_t, h);
}
__device__ __forceinline__ bf16x8 ldb8(const uint16_t* p) {
  return __builtin_bit_cast(bf16x8, *reinterpret_cast<const u16x8*>(p));
}

using as1_void = __attribute__((address_space(1))) const void;
using as3_void = __attribute__((address_space(3))) void;
__device__ __forceinline__ void gload16(const uint16_t* src, uint16_t* lds) {
  __builtin_amdgcn_global_load_lds((as1_void*)src, (as3_void*)lds, 16, 0, 0);
}
#define MEMFENCE asm volatile("" ::: "memory")

// ---------------- fused fp32 -> bf16 casts ----------------
#define N_QKVW  (3 * DMODEL * DMODEL)
#define N_PROJW (DMODEL * DMODEL)
#define N_FC1W  (HIDDEN * DMODEL)
#define N_FC2W  (DMODEL * HIDDEN)
__global__ __launch_bounds__(256) void cvt4_kernel(const float* __restrict__ s0,
                                                   const float* __restrict__ s1,
                                                   const float* __restrict__ s2,
                                                   const float* __restrict__ s3,
                                                   uint16_t* __restrict__ d0,
                                                   uint16_t* __restrict__ d1,
                                                   uint16_t* __restrict__ d2,
                                                   uint16_t* __restrict__ d3) {
  int i4 = (blockIdx.x * 256 + threadIdx.x) * 4;
  const float* s;
  uint16_t* d;
  if (i4 < N_QKVW) { s = s0 + i4; d = d0 + i4; }
  else if (i4 < N_QKVW + N_PROJW) { int j = i4 - N_QKVW; s = s1 + j; d = d1 + j; }
  else if (i4 < N_QKVW + N_PROJW + N_FC1W) { int j = i4 - N_QKVW - N_PROJW; s = s2 + j; d = d2 + j; }
  else { int j = i4 - N_QKVW - N_PROJW - N_FC1W; s = s3 + j; d = d3 + j; }
  float4 v = *reinterpret_cast<const float4*>(s);
  ushort4 o;
  o.x = f2bf(v.x); o.y = f2bf(v.y); o.z = f2bf(v.z); o.w = f2bf(v.w);
  *reinterpret_cast<ushort4*>(d) = o;
}

// ---------------- qkv bias assembly ----------------
__global__ __launch_bounds__(256) void bias_kernel(const float* __restrict__ qb,
                                                   const float* __restrict__ vb,
                                                   float* __restrict__ out) {
  int j = blockIdx.x * 256 + threadIdx.x;
  if (j < 3 * DMODEL) {
    float v = 0.f;
    if (j < DMODEL) v = qb[j];
    else if (j >= 2 * DMODEL) v = vb[j - 2 * DMODEL];
    out[j] = v;
  }
}

// ---------------- layernorm: fp32 in -> bf16 out ----------------
__global__ __launch_bounds__(256) void ln_kernel(const float* __restrict__ x,
                                                 const float* __restrict__ g,
                                                 const float* __restrict__ bt,
                                                 uint16_t* __restrict__ out) {
  const int row = blockIdx.x;
  const int t = threadIdx.x;
  const float* xr = x + (size_t)row * DMODEL;
  float v0 = xr[t], v1 = xr[t + 256], v2 = xr[t + 512];
  float s = v0 + v1 + v2;
  float q = v0 * v0 + v1 * v1 + v2 * v2;
  for (int off = 32; off >= 1; off >>= 1) {
    s += __shfl_xor(s, off);
    q += __shfl_xor(q, off);
  }
  __shared__ float ss[4], sq[4];
  int w = t >> 6;
  if ((t & 63) == 0) { ss[w] = s; sq[w] = q; }
  __syncthreads();
  s = ss[0] + ss[1] + ss[2] + ss[3];
  q = sq[0] + sq[1] + sq[2] + sq[3];
  const float mean = s * (1.0f / DMODEL);
  const float var = q * (1.0f / DMODEL) - mean * mean;
  const float rstd = rsqrtf(var + 1e-5f);
  uint16_t* orow = out + (size_t)row * DMODEL;
  orow[t]       = f2bf((v0 - mean) * rstd * g[t]       + bt[t]);
  orow[t + 256] = f2bf((v1 - mean) * rstd * g[t + 256] + bt[t + 256]);
  orow[t + 512] = f2bf((v2 - mean) * rstd * g[t + 512] + bt[t + 512]);
}

// ------------- GEMM A: 128x128 block, 4 waves x (64x64), dbuf counted-vmcnt ----
// MODE 0: out bf16 = acc+bias (q cols pre-scaled 0.125)   MODE 2: gelu -> bf16
template <int MODE>
__global__ __launch_bounds__(256, 3) void gemm128(const uint16_t* __restrict__ A,
                                                  const uint16_t* __restrict__ W,
                                                  const float* __restrict__ bias,
                                                  void* __restrict__ outp,
                                                  int M, int N, int K) {
  __shared__ uint16_t As[2][128 * 32];
  __shared__ uint16_t Bs[2][128 * 32];
  const int tid = threadIdx.x;
  const int lane = tid & 63;
  const int w = tid >> 6;
  const int wr = w >> 1, wc = w & 1;
  const int row0 = blockIdx.y * 128;
  const int col0 = blockIdx.x * 128;
  const int lr = lane & 15;
  const int g = lane >> 4;

  const int o0 = w * 1024 + lane * 16;
  const int o1 = o0 + 4096;
  const int r0s = o0 >> 6, c0s = (o0 & 63) >> 1;
  const int r1s = o1 >> 6, c1s = (o1 & 63) >> 1;
  const int l0 = (w * 1024) >> 1;
  const int l1 = l0 + 2048;
  const uint16_t* Abase = A + (size_t)row0 * K;
  const uint16_t* Wbase = W + (size_t)col0 * K;

  auto stage = [&](int kt) {
    uint16_t* Ad = &As[kt & 1][0];
    uint16_t* Bd = &Bs[kt & 1][0];
    const int kk = kt * 32;
    gload16(Abase + (size_t)r0s * K + kk + c0s, Ad + l0);
    gload16(Abase + (size_t)r1s * K + kk + c1s, Ad + l1);
    gload16(Wbase + (size_t)r0s * K + kk + c0s, Bd + l0);
    gload16(Wbase + (size_t)r1s * K + kk + c1s, Bd + l1);
  };

  f32x4 acc[4][4] = {};
  const int nt = K >> 5;
  stage(0);
  for (int kt = 0; kt < nt; ++kt) {
    if (kt + 1 < nt) {
      stage(kt + 1);
      asm volatile("s_waitcnt vmcnt(4)" ::: "memory");
    } else {
      asm volatile("s_waitcnt vmcnt(0)" ::: "memory");
    }
    __builtin_amdgcn_s_barrier();
    MEMFENCE;
    const uint16_t* Ab = &As[kt & 1][0];
    const uint16_t* Bb = &Bs[kt & 1][0];
    bf16x8 a[4], b[4];
#pragma unroll
    for (int m = 0; m < 4; ++m) a[m] = ldb8(Ab + (wr * 64 + m * 16 + lr) * 32 + g * 8);
#pragma unroll
    for (int n = 0; n < 4; ++n) b[n] = ldb8(Bb + (wc * 64 + n * 16 + lr) * 32 + g * 8);
#pragma unroll
    for (int m = 0; m < 4; ++m)
#pragma unroll
      for (int n = 0; n < 4; ++n)
        acc[m][n] = __builtin_amdgcn_mfma_f32_16x16x32_bf16(a[m], b[n], acc[m][n], 0, 0, 0);
    MEMFENCE;
    __builtin_amdgcn_s_barrier();
  }

#pragma unroll
  for (int m = 0; m < 4; ++m) {
    int row = row0 + wr * 64 + m * 16 + g * 4;
#pragma unroll
    for (int n = 0; n < 4; ++n) {
      int col = col0 + wc * 64 + n * 16 + lr;
      float bv = bias[col];
#pragma unroll
      for (int ri = 0; ri < 4; ++ri) {
        float val = acc[m][n][ri] + bv;
        size_t idx = (size_t)(row + ri) * N + col;
        if constexpr (MODE == 0) {
          if (col < DMODEL) val *= 0.125f;
          ((uint16_t*)outp)[idx] = f2bf(val);
        } else {
          float ge = 0.5f * val * (1.0f + erff(val * 0.70710678118654752f));
          ((uint16_t*)outp)[idx] = f2bf(ge);
        }
      }
    }
  }
}

// ------------- GEMM B: 128x64 block (for N=768 shapes -> 384 blocks) -----------
// 4 waves 2x2: wave = 64 rows x 32 cols. out f32 = resid + gamma*(acc+bias)
__global__ __launch_bounds__(256, 3) void gemm64(const uint16_t* __restrict__ A,
                                                 const uint16_t* __restrict__ W,
                                                 const float* __restrict__ bias,
                                                 float* __restrict__ outp,
                                                 const float* __restrict__ resid,
                                                 const float* __restrict__ gamma,
                                                 int M, int N, int K) {
  __shared__ uint16_t As[2][128 * 32];
  __shared__ uint16_t Bs[2][64 * 32];
  const int tid = threadIdx.x;
  const int lane = tid & 63;
  const int w = tid >> 6;
  const int wr = w >> 1, wc = w & 1;
  const int row0 = blockIdx.y * 128;
  const int col0 = blockIdx.x * 64;
  const int lr = lane & 15;
  const int g = lane >> 4;

  const int o0 = w * 1024 + lane * 16;
  const int o1 = o0 + 4096;
  const int r0s = o0 >> 6, c0s = (o0 & 63) >> 1;   // A rows 0..63 / 64..127
  const int r1s = o1 >> 6, c1s = (o1 & 63) >> 1;
  const int l0 = (w * 1024) >> 1;
  const int l1 = l0 + 2048;
  const uint16_t* Abase = A + (size_t)row0 * K;
  const uint16_t* Wbase = W + (size_t)col0 * K;

  auto stage = [&](int kt) {
    uint16_t* Ad = &As[kt & 1][0];
    uint16_t* Bd = &Bs[kt & 1][0];
    const int kk = kt * 32;
    gload16(Abase + (size_t)r0s * K + kk + c0s, Ad + l0);
    gload16(Abase + (size_t)r1s * K + kk + c1s, Ad + l1);
    gload16(Wbase + (size_t)r0s * K + kk + c0s, Bd + l0);  // B rows 0..63
  };

  f32x4 acc[4][2] = {};
  const int nt = K >> 5;
  stage(0);
  for (int kt = 0; kt < nt; ++kt) {
    if (kt + 1 < nt) {
      stage(kt + 1);
      asm volatile("s_waitcnt vmcnt(3)" ::: "memory");
    } else {
      asm volatile("s_waitcnt vmcnt(0)" ::: "memory");
    }
    __builtin_amdgcn_s_barrier();
    MEMFENCE;
    const uint16_t* Ab = &As[kt & 1][0];
    const uint16_t* Bb = &Bs[kt & 1][0];
    bf16x8 a[4], b[2];
#pragma unroll
    for (int m = 0; m < 4; ++m) a[m] = ldb8(Ab + (wr * 64 + m * 16 + lr) * 32 + g * 8);
#pragma unroll
    for (int n = 0; n < 2; ++n) b[n] = ldb8(Bb + (wc * 32 + n * 16 + lr) * 32 + g * 8);
#pragma unroll
    for (int m = 0; m < 4; ++m)
#pragma unroll
      for (int n = 0; n < 2; ++n)
        acc[m][n] = __builtin_amdgcn_mfma_f32_16x16x32_bf16(a[m], b[n], acc[m][n], 0, 0, 0);
    MEMFENCE;
    __builtin_amdgcn_s_barrier();
  }

#pragma unroll
  for (int m = 0; m < 4; ++m) {
    int row = row0 + wr * 64 + m * 16 + g * 4;
#pragma unroll
    for (int n = 0; n < 2; ++n) {
      int col = col0 + wc * 32 + n * 16 + lr;
      float bv = bias[col];
      float gv = gamma[col];
#pragma unroll
      for (int ri = 0; ri < 4; ++ri) {
        float val = acc[m][n][ri] + bv;
        size_t idx = (size_t)(row + ri) * N + col;
        outp[idx] = resid[idx] + gv * val;
      }
    }
  }
}

// ---------------- V transpose (LDS-tiled, coalesced): qkv -> vt[bh][d][n] ------
__global__ __launch_bounds__(256) void vtrans_kernel(const uint16_t* __restrict__ qkv,
                                                     uint16_t* __restrict__ vt) {
  __shared__ uint16_t tile[64][72];
  const int t = threadIdx.x;
  const int bh = blockIdx.x;
  const int n0 = blockIdx.y * 64;
  const int b = bh / NHEAD, h = bh % NHEAD;
  const uint16_t* src = qkv + (size_t)(b * NSEQ + n0) * (3 * DMODEL) + 2 * DMODEL + h * HDIM;
#pragma unroll
  for (int it = 0; it < 2; ++it) {
    int slot = it * 256 + t;
    int r = slot >> 2, c = (slot & 3) * 16;
    u16x8 v0 = *reinterpret_cast<const u16x8*>(src + (size_t)r * (3 * DMODEL) + c);
    u16x8 v1 = *reinterpret_cast<const u16x8*>(src + (size_t)r * (3 * DMODEL) + c + 8);
    *reinterpret_cast<u16x8*>(&tile[r][c]) = v0;
    *reinterpret_cast<u16x8*>(&tile[r][c + 8]) = v1;
  }
  __syncthreads();
  uint16_t* dst = vt + (size_t)bh * HDIM * NSEQ + n0;
#pragma unroll
  for (int it = 0; it < 2; ++it) {
    int slot = it * 256 + t;
    int d = slot >> 2, c = (slot & 3) * 16;
    u16x8 a0, a1;
#pragma unroll
    for (int e = 0; e < 8; ++e) a0[e] = tile[c + e][d];
#pragma unroll
    for (int e = 0; e < 8; ++e) a1[e] = tile[c + 8 + e][d];
    *reinterpret_cast<u16x8*>(dst + (size_t)d * NSEQ + c) = a0;
    *reinterpret_cast<u16x8*>(dst + (size_t)d * NSEQ + c + 8) = a1;
  }
}

// ---------------- flash attention v3 -------------------------------------------
// 4 waves x 32 q-rows, KVBLK=64, LDS dbuf K/V + counted vmcnt, ones-MFMA lsum,
// setprio on MFMA clusters, mask as 64-bit ballot words (256B LDS).
__global__ __launch_bounds__(256, 2) void attn_kernel(const uint16_t* __restrict__ qkv,
                                                      const uint16_t* __restrict__ vt,
                                                      const int* __restrict__ mask,
                                                      uint16_t* __restrict__ o) {
  __shared__ uint16_t Kb[2][64 * 64];
  __shared__ uint16_t Vb[2][64 * 64];
  __shared__ __align__(16) uint16_t plds[4][2][16 * 72];
  __shared__ unsigned long long mbits[NSEQ / 64];
  const int tid = threadIdx.x;
  const int lane = tid & 63;
  const int w = tid >> 6;
  const int bh = blockIdx.x;
  const int b = bh / NHEAD, h = bh % NHEAD;
  const int q0 = blockIdx.y * 128 + w * 32;
  const int lr = lane & 15;
  const int g = lane >> 4;
  const int lk = g * 8;

  // mask -> one 64-bit word per KV tile via ballot
  const int* mb = mask + b * NSEQ;
#pragma unroll
  for (int it = 0; it < NSEQ / 256; ++it) {
    unsigned long long bm = __ballot(mb[it * 256 + tid] != 0);
    if (lane == 0) mbits[it * 4 + w] = bm;
  }

  bf16x8 qa[2][2];
#pragma unroll
  for (int s = 0; s < 2; ++s) {
    const uint16_t* qb = qkv + (size_t)(b * NSEQ + q0 + s * 16 + lr) * (3 * DMODEL) + h * HDIM + lk;
    qa[s][0] = ldb8(qb);
    qa[s][1] = ldb8(qb + 32);
  }
  const uint16_t* kglob = qkv + (size_t)b * NSEQ * (3 * DMODEL) + DMODEL + h * HDIM;
  const uint16_t* vtb = vt + (size_t)bh * HDIM * NSEQ;

  __syncthreads();   // mbits visible before loop

  const int srow = tid >> 3;
  const int sxor = ((tid & 7) ^ ((tid >> 3) & 7)) * 8;
  auto stage = [&](int t) {
    const int p = t & 1;
    const int k0 = t * 64;
#pragma unroll
    for (int i = 0; i < 2; ++i) {
      const int row = i * 32 + srow;
      gload16(kglob + (size_t)(k0 + row) * (3 * DMODEL) + sxor, &Kb[p][i * 2048 + w * 512]);
      gload16(vtb + (size_t)row * NSEQ + k0 + sxor, &Vb[p][i * 2048 + w * 512]);
    }
  };
  const int koff0 = ((g ^ (lr & 7))) * 8;
  const int koff1 = (((4 + g) ^ (lr & 7))) * 8;

  u16x8 ones_u;
#pragma unroll
  for (int e = 0; e < 8; ++e) ones_u[e] = 0x3F80;
  const bf16x8 ones = __builtin_bit_cast(bf16x8, ones_u);

  float m_[2][4] = {{-1e30f, -1e30f, -1e30f, -1e30f}, {-1e30f, -1e30f, -1e30f, -1e30f}};
  f32x4 lsum[2] = {};
  f32x4 oacc[2][4] = {};

  stage(0);
  const int NT = NSEQ / 64;
  for (int t = 0; t < NT; ++t) {
    if (t + 1 < NT) {
      stage(t + 1);
      asm volatile("s_waitcnt vmcnt(4)" ::: "memory");
    } else {
      asm volatile("s_waitcnt vmcnt(0)" ::: "memory");
    }
    __builtin_amdgcn_s_barrier();
    MEMFENCE;
    const uint16_t* Kbp = &Kb[t & 1][0];
    const uint16_t* Vbp = &Vb[t & 1][0];

    f32x4 st[2][4];
    __builtin_amdgcn_s_setprio(1);
#pragma unroll
    for (int j = 0; j < 4; ++j) {
      const uint16_t* kr = Kbp + (j * 16 + lr) * 64;
      bf16x8 kf0 = ldb8(kr + koff0);
      bf16x8 kf1 = ldb8(kr + koff1);
#pragma unroll
      for (int s = 0; s < 2; ++s) {
        f32x4 acc0 = {};
        acc0 = __builtin_amdgcn_mfma_f32_16x16x32_bf16(qa[s][0], kf0, acc0, 0, 0, 0);
        acc0 = __builtin_amdgcn_mfma_f32_16x16x32_bf16(qa[s][1], kf1, acc0, 0, 0, 0);
        st[s][j] = acc0;
      }
    }
    __builtin_amdgcn_s_setprio(0);

    const unsigned long long wb = mbits[t];
    const uint32_t wlo = (uint32_t)wb, whi = (uint32_t)(wb >> 32);
    float bj[4];
    bj[0] = ((wlo >> lr) & 1) ? 0.f : -3e30f;
    bj[1] = ((wlo >> (16 + lr)) & 1) ? 0.f : -3e30f;
    bj[2] = ((whi >> lr) & 1) ? 0.f : -3e30f;
    bj[3] = ((whi >> (16 + lr)) & 1) ? 0.f : -3e30f;

    float sv[2][4][4], tmax[2][4];
    float need = 0.f;
#pragma unroll
    for (int s = 0; s < 2; ++s)
#pragma unroll
      for (int r = 0; r < 4; ++r) {
        float tm = -1e30f;
#pragma unroll
        for (int j = 0; j < 4; ++j) {
          float sc = st[s][j][r] + bj[j];
          sv[s][r][j] = sc;
          tm = fmaxf(tm, sc);
        }
        tm = fmaxf(tm, __shfl_xor(tm, 1));
        tm = fmaxf(tm, __shfl_xor(tm, 2));
        tm = fmaxf(tm, __shfl_xor(tm, 4));
        tm = fmaxf(tm, __shfl_xor(tm, 8));
        tmax[s][r] = tm;
        need = fmaxf(need, tm - m_[s][r]);
      }
    if (__any(need > 8.0f)) {           // defer-max (T13)
#pragma unroll
      for (int s = 0; s < 2; ++s)
#pragma unroll
        for (int r = 0; r < 4; ++r) {
          float mn = fmaxf(m_[s][r], tmax[s][r]);
          float al = __expf(m_[s][r] - mn);
          lsum[s][r] *= al;
          m_[s][r] = mn;
#pragma unroll
          for (int dt = 0; dt < 4; ++dt) oacc[s][dt][r] *= al;
        }
    }
#pragma unroll
    for (int s = 0; s < 2; ++s)
#pragma unroll
      for (int r = 0; r < 4; ++r)
#pragma unroll
        for (int j = 0; j < 4; ++j) {
          float pv = __expf(sv[s][r][j] - m_[s][r]);
          plds[w][s][(g * 4 + r) * 72 + j * 16 + lr] = f2bf(pv);
        }
    bf16x8 pa[2][2];
#pragma unroll
    for (int s = 0; s < 2; ++s) {
      pa[s][0] = ldb8(&plds[w][s][lr * 72 + lk]);
      pa[s][1] = ldb8(&plds[w][s][lr * 72 + 32 + lk]);
    }
    __builtin_amdgcn_s_setprio(1);
#pragma unroll
    for (int dt = 0; dt < 4; ++dt) {
      const uint16_t* vr = Vbp + (dt * 16 + lr) * 64;
      bf16x8 vf0 = ldb8(vr + koff0);
      bf16x8 vf1 = ldb8(vr + koff1);
#pragma unroll
      for (int s = 0; s < 2; ++s) {
        oacc[s][dt] = __builtin_amdgcn_mfma_f32_16x16x32_bf16(pa[s][0], vf0, oacc[s][dt], 0, 0, 0);
        oacc[s][dt] = __builtin_amdgcn_mfma_f32_16x16x32_bf16(pa[s][1], vf1, oacc[s][dt], 0, 0, 0);
      }
    }
#pragma unroll
    for (int s = 0; s < 2; ++s) {
      lsum[s] = __builtin_amdgcn_mfma_f32_16x16x32_bf16(pa[s][0], ones, lsum[s], 0, 0, 0);
      lsum[s] = __builtin_amdgcn_mfma_f32_16x16x32_bf16(pa[s][1], ones, lsum[s], 0, 0, 0);
    }
    __builtin_amdgcn_s_setprio(0);
    MEMFENCE;
    __builtin_amdgcn_s_barrier();
  }

#pragma unroll
  for (int s = 0; s < 2; ++s) {
    float inv[4];
#pragma unroll
    for (int r = 0; r < 4; ++r) inv[r] = lsum[s][r] > 0.f ? 1.f / lsum[s][r] : 0.f;
    uint16_t* ob = o + (size_t)(b * NSEQ + q0 + s * 16) * DMODEL + h * HDIM;
#pragma unroll
    for (int dt = 0; dt < 4; ++dt)
#pragma unroll
      for (int r = 0; r < 4; ++r)
        ob[(size_t)(g * 4 + r) * DMODEL + dt * 16 + lr] = f2bf(oacc[s][dt][r] * inv[r]);
  }
}

// ---------------- host ----------------
extern "C" void kernel_launch(void* const* d_in, const int* in_sizes, int n_in,
                              void* d_out, int out_size, void* d_ws, size_t ws_size,
                              hipStream_t stream) {
  const float* x      = (const float*)d_in[0];
  const int*   amask  = (const int*)d_in[1];
  const float* ln1_g  = (const float*)d_in[2];
  const float* ln1_b  = (const float*)d_in[3];
  const float* qkv_w  = (const float*)d_in[4];
  const float* q_bias = (const float*)d_in[5];
  const float* v_bias = (const float*)d_in[6];
  const float* proj_w = (const float*)d_in[7];
  const float* proj_b = (const float*)d_in[8];
  const float* ln2_g  = (const float*)d_in[9];
  const float* ln2_b  = (const float*)d_in[10];
  const float* fc1_w  = (const float*)d_in[11];
  const float* fc1_b  = (const float*)d_in[12];
  const float* fc2_w  = (const float*)d_in[13];
  const float* fc2_b  = (const float*)d_in[14];
  const float* g1     = (const float*)d_in[15];
  const float* g2     = (const float*)d_in[16];

  char* ws = (char*)d_ws;
  uint16_t* qkvw_bf  = (uint16_t*)(ws + 0);
  uint16_t* projw_bf = (uint16_t*)(ws + 3538944);
  uint16_t* fc1w_bf  = (uint16_t*)(ws + 4718592);
  uint16_t* fc2w_bf  = (uint16_t*)(ws + 9437184);
  float*    qkvbias  = (float*)(ws + 14155776);
  uint16_t* h_bf     = (uint16_t*)(ws + 14164992);
  uint16_t* qkv_bf   = (uint16_t*)(ws + 20456448);
  uint16_t* vt_bf    = (uint16_t*)(ws + 39330816);
  uint16_t* o_bf     = (uint16_t*)(ws + 45622272);
  float*    x1_f     = (float*)(ws + 51913728);
  uint16_t* fc1_bf   = qkv_bf;
  uint16_t* h2_bf    = h_bf;

  const int M = BATCH * NSEQ;

  cvt4_kernel<<<(N_QKVW + N_PROJW + N_FC1W + N_FC2W) / 1024, 256, 0, stream>>>(
      qkv_w, proj_w, fc1_w, fc2_w, qkvw_bf, projw_bf, fc1w_bf, fc2w_bf);
  bias_kernel<<<(3 * DMODEL + 255) / 256, 256, 0, stream>>>(q_bias, v_bias, qkvbias);

  ln_kernel<<<M, 256, 0, stream>>>(x, ln1_g, ln1_b, h_bf);
  gemm128<0><<<dim3((3 * DMODEL) / 128, M / 128), 256, 0, stream>>>(
      h_bf, qkvw_bf, qkvbias, qkv_bf, M, 3 * DMODEL, DMODEL);
  vtrans_kernel<<<dim3(BATCH * NHEAD, NSEQ / 64), 256, 0, stream>>>(qkv_bf, vt_bf);
  attn_kernel<<<dim3(BATCH * NHEAD, NSEQ / 128), 256, 0, stream>>>(qkv_bf, vt_bf, amask, o_bf);
  gemm64<<<dim3(DMODEL / 64, M / 128), 256, 0, stream>>>(
      o_bf, projw_bf, proj_b, x1_f, x, g1, M, DMODEL, DMODEL);
  ln_kernel<<<M, 256, 0, stream>>>(x1_f, ln2_g, ln2_b, h2_bf);
  gemm128<2><<<dim3(HIDDEN / 128, M / 128), 256, 0, stream>>>(
      h2_bf, fc1w_bf, fc1_b, fc1_bf, M, HIDDEN, DMODEL);
  gemm64<<<dim3(DMODEL / 64, M / 128), 256, 0, stream>>>(
      fc1_bf, fc2w_bf, fc2_b, (float*)d_out, x1_f, g2, M, DMODEL, HIDDEN);
}